// Round 1
// baseline (379.112 us; speedup 1.0000x reference)
//
#include <hip/hip_runtime.h>

// GCNConv + residual + ReLU, fp32.
//   x  [N,64]  d_in[0]  float
//   W  [64,64] d_in[1]  float   (h = x @ W^T, i.e. h[i][j] = sum_k x[i][k]*W[j][k])
//   b  [64]    d_in[2]  float
//   ei [2,E]   d_in[3]  int32   (src = ei[0..E), dst = ei[E..2E))
// out [N,64] float
//
// ws layout: deg int[N] @0 ; dinv float[N] @400000 ; h float[N*64] @800000
// total ~26.4 MB.

#define NN 100000
#define NE 800000
#define DD 64

__global__ void deg_kernel(const int* __restrict__ ei, int* __restrict__ deg) {
    int e = blockIdx.x * blockDim.x + threadIdx.x;
    if (e < NE) {
        atomicAdd(&deg[ei[NE + e]], 1);
    }
}

__global__ void dinv_kernel(const int* __restrict__ deg, float* __restrict__ dinv) {
    int i = blockIdx.x * blockDim.x + threadIdx.x;
    if (i < NN) {
        dinv[i] = rsqrtf((float)deg[i] + 1.0f);  // +1 self-loop
    }
}

// h = x @ W^T. Block = 256 threads = 4 rows x 64 cols.
// W staged in LDS transposed with +1 pad: Ws[k*65+j] = W[j*64+k]
// -> inner-loop read Ws[k*65+col] is stride-1 across lanes (conflict-free).
__global__ __launch_bounds__(256) void linear_kernel(const float* __restrict__ x,
                                                     const float* __restrict__ W,
                                                     float* __restrict__ h) {
    __shared__ float Ws[64 * 65];
    __shared__ float xs[4 * 64];
    int t = threadIdx.x;
#pragma unroll
    for (int m = t; m < 4096; m += 256) {
        int j = m >> 6, k = m & 63;
        Ws[k * 65 + j] = W[m];
    }
    int rowBase = blockIdx.x * 4;
    xs[t] = x[rowBase * 64 + t];  // 4 contiguous rows, coalesced
    __syncthreads();
    int rl = t >> 6;    // local row 0..3
    int col = t & 63;
    float acc = 0.f;
#pragma unroll
    for (int k = 0; k < 64; ++k)
        acc += xs[rl * 64 + k] * Ws[k * 65 + col];
    h[(rowBase + rl) * 64 + col] = acc;
}

// One lane per (edge, column): wave = 1 edge x 64 cols.
// s,d,w wave-uniform; h read coalesced 256B; 64 atomics into out[d][:].
__global__ void scatter_kernel(const int* __restrict__ ei,
                               const float* __restrict__ dinv,
                               const float* __restrict__ h,
                               float* __restrict__ out) {
    int tid = blockIdx.x * blockDim.x + threadIdx.x;
    int e = tid >> 6;
    int j = tid & 63;
    if (e < NE) {
        int s = ei[e];
        int d = ei[NE + e];
        float w = dinv[s] * dinv[d];
        atomicAdd(&out[d * 64 + j], h[s * 64 + j] * w);
    }
}

// out = relu(out + h*dinv^2 (self-loop msg) + b + x)
__global__ void final_kernel(const float* __restrict__ x,
                             const float* __restrict__ b,
                             const float* __restrict__ h,
                             const float* __restrict__ dinv,
                             float* __restrict__ out) {
    int tid = blockIdx.x * blockDim.x + threadIdx.x;
    if (tid < NN * DD) {
        int i = tid >> 6;
        int j = tid & 63;
        float di = dinv[i];
        float v = out[tid] + h[tid] * di * di + b[j] + x[tid];
        out[tid] = fmaxf(v, 0.f);
    }
}

extern "C" void kernel_launch(void* const* d_in, const int* in_sizes, int n_in,
                              void* d_out, int out_size, void* d_ws, size_t ws_size,
                              hipStream_t stream) {
    const float* x = (const float*)d_in[0];
    const float* W = (const float*)d_in[1];
    const float* b = (const float*)d_in[2];
    const int* ei = (const int*)d_in[3];
    float* out = (float*)d_out;

    char* ws = (char*)d_ws;
    int* deg    = (int*)ws;
    float* dinv = (float*)(ws + 400000);
    float* h    = (float*)(ws + 800000);

    hipMemsetAsync(deg, 0, NN * sizeof(int), stream);
    hipMemsetAsync(out, 0, (size_t)NN * DD * sizeof(float), stream);

    deg_kernel<<<(NE + 255) / 256, 256, 0, stream>>>(ei, deg);
    dinv_kernel<<<(NN + 255) / 256, 256, 0, stream>>>(deg, dinv);
    linear_kernel<<<NN / 4, 256, 0, stream>>>(x, W, h);
    scatter_kernel<<<(NE * DD) / 256, 256, 0, stream>>>(ei, dinv, h, out);
    final_kernel<<<(NN * DD + 255) / 256, 256, 0, stream>>>(x, b, h, dinv, out);
}

// Round 2
// 318.331 us; speedup vs baseline: 1.1909x; 1.1909x over previous
//
#include <hip/hip_runtime.h>

// GCNConv + residual + ReLU, fp32 — CSR-gather formulation (no fp32 atomics).
//   x  [N,64]  d_in[0]  float
//   W  [64,64] d_in[1]  float   (h = x @ W^T)
//   b  [64]    d_in[2]  float
//   ei [2,E]   d_in[3]  int32   (src = ei[0..E), dst = ei[E..2E))
// out [N,64] float
//
// Pipeline per call:
//   deg[dst]++ (int atomics) -> dinv = rsqrt(deg+1)
//   exclusive scan(deg) -> offs            (3 small kernels)
//   bin: pos = atomicAdd(&offs[d],1); srcIdx[pos] = s   (offs becomes END)
//   linear: h = x @ W^T
//   gather (fused epilogue): out[i][:] = relu(dinv[i]*sum_s dinv[s]*h[s][:]
//                                             + dinv[i]^2*h[i][:] + b + x[i][:])

#define NN 100000
#define NE 800000
#define DD 64
#define SCAN_B 1024
#define SCAN_NB 98   // ceil(100000/1024)

__global__ void deg_kernel(const int* __restrict__ ei, int* __restrict__ deg) {
    int e = blockIdx.x * blockDim.x + threadIdx.x;
    if (e < NE) atomicAdd(&deg[ei[NE + e]], 1);
}

__global__ void dinv_kernel(const int* __restrict__ deg, float* __restrict__ dinv) {
    int i = blockIdx.x * blockDim.x + threadIdx.x;
    if (i < NN) dinv[i] = rsqrtf((float)deg[i] + 1.0f);  // +1 self-loop
}

// ---- 3-kernel exclusive scan of deg -> offs ----
__global__ __launch_bounds__(SCAN_B) void scan1_kernel(const int* __restrict__ deg,
                                                       int* __restrict__ offs,
                                                       int* __restrict__ bsum) {
    __shared__ int tmp[SCAN_B];
    int t = threadIdx.x;
    int i = blockIdx.x * SCAN_B + t;
    int v = (i < NN) ? deg[i] : 0;
    tmp[t] = v;
    __syncthreads();
    for (int off = 1; off < SCAN_B; off <<= 1) {
        int add = (t >= off) ? tmp[t - off] : 0;
        __syncthreads();
        tmp[t] += add;
        __syncthreads();
    }
    int incl = tmp[t];
    if (i < NN) offs[i] = incl - v;  // exclusive
    if (t == SCAN_B - 1) bsum[blockIdx.x] = incl;
}

__global__ void scan2_kernel(int* __restrict__ bsum) {
    __shared__ int s[SCAN_NB];
    int t = threadIdx.x;
    if (t < SCAN_NB) s[t] = bsum[t];
    __syncthreads();
    if (t == 0) {
        int acc = 0;
        for (int k = 0; k < SCAN_NB; ++k) { int v = s[k]; s[k] = acc; acc += v; }
    }
    __syncthreads();
    if (t < SCAN_NB) bsum[t] = s[t];
}

__global__ __launch_bounds__(SCAN_B) void scan3_kernel(int* __restrict__ offs,
                                                       const int* __restrict__ bsum) {
    int i = blockIdx.x * SCAN_B + threadIdx.x;
    if (i < NN) offs[i] += bsum[blockIdx.x];
}

// ---- bin edges by destination: offs[d] is cursor; after this, offs[d] = END ----
__global__ void bin_kernel(const int* __restrict__ ei, int* __restrict__ offs,
                           int* __restrict__ srcIdx) {
    int e = blockIdx.x * blockDim.x + threadIdx.x;
    if (e < NE) {
        int s = ei[e];
        int d = ei[NE + e];
        int pos = atomicAdd(&offs[d], 1);
        srcIdx[pos] = s;
    }
}

// ---- h = x @ W^T. Block = 256 threads = 4 rows x 64 cols. W^T staged in LDS, +1 pad. ----
__global__ __launch_bounds__(256) void linear_kernel(const float* __restrict__ x,
                                                     const float* __restrict__ W,
                                                     float* __restrict__ h) {
    __shared__ float Ws[64 * 65];
    __shared__ float xs[4 * 64];
    int t = threadIdx.x;
#pragma unroll
    for (int m = t; m < 4096; m += 256) {
        int j = m >> 6, k = m & 63;
        Ws[k * 65 + j] = W[m];
    }
    int rowBase = blockIdx.x * 4;
    xs[t] = x[rowBase * 64 + t];
    __syncthreads();
    int rl = t >> 6;
    int col = t & 63;
    float acc = 0.f;
#pragma unroll
    for (int k = 0; k < 64; ++k)
        acc += xs[rl * 64 + k] * Ws[k * 65 + col];
    h[(rowBase + rl) * 64 + col] = acc;
}

// ---- gather + fused epilogue. One wave per node, lane per column. ----
__global__ __launch_bounds__(256) void gather_kernel(const int* __restrict__ srcIdx,
                                                     const int* __restrict__ deg,
                                                     const int* __restrict__ ends,
                                                     const float* __restrict__ dinv,
                                                     const float* __restrict__ h,
                                                     const float* __restrict__ x,
                                                     const float* __restrict__ b,
                                                     float* __restrict__ out) {
    int tid = blockIdx.x * blockDim.x + threadIdx.x;
    int i = tid >> 6;   // node (one wave each)
    int j = tid & 63;   // column
    if (i >= NN) return;
    int end = ends[i];
    int beg = end - deg[i];
    float acc = 0.f;
    for (int p = beg; p < end; ++p) {
        int s = srcIdx[p];               // wave-uniform (broadcast)
        acc += h[s * 64 + j] * dinv[s];  // coalesced 256B row read
    }
    float di = dinv[i];
    float v = di * acc + di * di * h[i * 64 + j] + b[j] + x[i * 64 + j];
    out[i * 64 + j] = fmaxf(v, 0.f);
}

extern "C" void kernel_launch(void* const* d_in, const int* in_sizes, int n_in,
                              void* d_out, int out_size, void* d_ws, size_t ws_size,
                              hipStream_t stream) {
    const float* x = (const float*)d_in[0];
    const float* W = (const float*)d_in[1];
    const float* b = (const float*)d_in[2];
    const int* ei = (const int*)d_in[3];
    float* out = (float*)d_out;

    char* ws = (char*)d_ws;
    int*   deg    = (int*)(ws + 0);          //   400,000 B
    float* dinv   = (float*)(ws + 400128);   //   400,000 B
    int*   offs   = (int*)(ws + 800256);     //   400,000 B
    int*   bsum   = (int*)(ws + 1200384);    //       512 B
    int*   srcIdx = (int*)(ws + 1200896);    // 3,200,000 B
    float* h      = (float*)(ws + 4400896);  // 25,600,000 B  (16B aligned)

    hipMemsetAsync(deg, 0, NN * sizeof(int), stream);

    deg_kernel<<<(NE + 255) / 256, 256, 0, stream>>>(ei, deg);
    dinv_kernel<<<(NN + 255) / 256, 256, 0, stream>>>(deg, dinv);
    scan1_kernel<<<SCAN_NB, SCAN_B, 0, stream>>>(deg, offs, bsum);
    scan2_kernel<<<1, 128, 0, stream>>>(bsum);
    scan3_kernel<<<SCAN_NB, SCAN_B, 0, stream>>>(offs, bsum);
    bin_kernel<<<(NE + 255) / 256, 256, 0, stream>>>(ei, offs, srcIdx);
    linear_kernel<<<NN / 4, 256, 0, stream>>>(x, W, h);
    gather_kernel<<<(NN * DD + 255) / 256, 256, 0, stream>>>(srcIdx, deg, offs, dinv, h, x, b, out);
}

// Round 3
// 262.501 us; speedup vs baseline: 1.4442x; 1.2127x over previous
//
#include <hip/hip_runtime.h>

// GCNConv + residual + ReLU, fp32 in/out — CSR-gather, bf16 pre-scaled messages.
//   x  [N,64]  d_in[0]  float
//   W  [64,64] d_in[1]  float   (h = x @ W^T)
//   b  [64]    d_in[2]  float
//   ei [2,E]   d_in[3]  int32   (src = ei[0..E), dst = ei[E..2E))
// out [N,64] float
//
// h'[s][:] = bf16( dinv[s] * (x @ W^T)[s][:] )   (12.8 MB, gather-friendly)
// out[i]   = relu( dinv[i] * (h'[i] + sum_{s->i} h'[s]) + b + x[i] )

#define NN 100000
#define NE 800000
#define DD 64
#define SCAN_B 1024
#define SCAN_NB 98   // ceil(100000/1024)

typedef unsigned int uint;
typedef unsigned short ushort;

__device__ __forceinline__ ushort f2bf(float f) {
    uint u = __float_as_uint(f);
    u += 0x7fffu + ((u >> 16) & 1u);   // round-to-nearest-even
    return (ushort)(u >> 16);
}
__device__ __forceinline__ float bflo(uint u) { return __uint_as_float(u << 16); }
__device__ __forceinline__ float bfhi(uint u) { return __uint_as_float(u & 0xffff0000u); }

__global__ void deg_kernel(const int* __restrict__ ei, int* __restrict__ deg) {
    int e = blockIdx.x * blockDim.x + threadIdx.x;
    if (e < NE) atomicAdd(&deg[ei[NE + e]], 1);
}

// scan1: per-block exclusive scan of deg -> offs (block-local), block totals -> bsum.
// Fused: dinv = rsqrt(deg+1).
__global__ __launch_bounds__(SCAN_B) void scan1_kernel(const int* __restrict__ deg,
                                                       int* __restrict__ offs,
                                                       int* __restrict__ bsum,
                                                       float* __restrict__ dinv) {
    __shared__ int tmp[SCAN_B];
    int t = threadIdx.x;
    int i = blockIdx.x * SCAN_B + t;
    int v = (i < NN) ? deg[i] : 0;
    if (i < NN) dinv[i] = rsqrtf((float)v + 1.0f);  // +1 self-loop
    tmp[t] = v;
    __syncthreads();
    for (int off = 1; off < SCAN_B; off <<= 1) {
        int add = (t >= off) ? tmp[t - off] : 0;
        __syncthreads();
        tmp[t] += add;
        __syncthreads();
    }
    int incl = tmp[t];
    if (i < NN) offs[i] = incl - v;  // block-local exclusive
    if (t == SCAN_B - 1) bsum[blockIdx.x] = incl;
}

__global__ void scan2_kernel(int* __restrict__ bsum) {
    __shared__ int s[SCAN_NB];
    int t = threadIdx.x;
    if (t < SCAN_NB) s[t] = bsum[t];
    __syncthreads();
    if (t == 0) {
        int acc = 0;
        for (int k = 0; k < SCAN_NB; ++k) { int v = s[k]; s[k] = acc; acc += v; }
    }
    __syncthreads();
    if (t < SCAN_NB) bsum[t] = s[t];
}

// bin: pos = (local cursor)++ + bsum[d/1024]  -> global slot. offs stays local.
__global__ void bin_kernel(const int* __restrict__ ei, int* __restrict__ offs,
                           const int* __restrict__ bsum, int* __restrict__ srcIdx) {
    int e = blockIdx.x * blockDim.x + threadIdx.x;
    if (e < NE) {
        int s = ei[e];
        int d = ei[NE + e];
        int pos = atomicAdd(&offs[d], 1) + bsum[d >> 10];
        srcIdx[pos] = s;
    }
}

// linear: h' = bf16(dinv * (x @ W^T)). Block = 256 = 16 rows x 16 col-quads.
// LDS W^T scalar layout read as float4: Wv[k*16+rq] -> 16 distinct 16B addrs,
// lanes rq and rq+8 alias banks 2-way (free).
__global__ __launch_bounds__(256) void linear_kernel(const float* __restrict__ x,
                                                     const float* __restrict__ W,
                                                     const float* __restrict__ dinv,
                                                     ushort* __restrict__ hq) {
    __shared__ float Ws2[64 * 64];   // Ws2[k*64 + j] = W[j*64 + k]
    __shared__ float xs[16 * 64];
    int t = threadIdx.x;
#pragma unroll
    for (int m = t; m < 4096; m += 256) {
        int j = m >> 6, k = m & 63;
        Ws2[k * 64 + j] = W[m];
    }
    int rowBase = blockIdx.x * 16;
#pragma unroll
    for (int m = t; m < 1024; m += 256) xs[m] = x[rowBase * 64 + m];
    __syncthreads();

    int rq = t & 15;     // column quad
    int row = t >> 4;    // local row 0..15
    const float4* Wv = (const float4*)Ws2;
    float4 acc = make_float4(0.f, 0.f, 0.f, 0.f);
#pragma unroll
    for (int k = 0; k < 64; ++k) {
        float xv = xs[row * 64 + k];
        float4 w = Wv[k * 16 + rq];
        acc.x += xv * w.x; acc.y += xv * w.y; acc.z += xv * w.z; acc.w += xv * w.w;
    }
    int rg = rowBase + row;
    float sc = dinv[rg];
    ushort4 o;
    o.x = f2bf(acc.x * sc); o.y = f2bf(acc.y * sc);
    o.z = f2bf(acc.z * sc); o.w = f2bf(acc.w * sc);
    ((ushort4*)hq)[rg * 16 + rq] = o;
}

// gather: 8 lanes per node, lane covers 8 columns (one uint4 = 8 bf16 per load).
// Edge loop unrolled x2 for MLP. Fused self-loop, bias, residual, ReLU.
__global__ __launch_bounds__(256) void gather_kernel(const int* __restrict__ srcIdx,
                                                     const int* __restrict__ deg,
                                                     const int* __restrict__ offs,
                                                     const int* __restrict__ bsum,
                                                     const float* __restrict__ dinv,
                                                     const uint4* __restrict__ hq4,
                                                     const float4* __restrict__ x4,
                                                     const float* __restrict__ b,
                                                     float4* __restrict__ out4) {
    int t = blockIdx.x * blockDim.x + threadIdx.x;
    int node = t >> 3;        // 32 nodes per block
    int l = t & 7;            // lane covers columns l*8 .. l*8+7
    if (node >= NN) return;

    int dg = deg[node];
    int end = offs[node] + bsum[node >> 10];
    int beg = end - dg;

    float acc[8];
    uint4 v = hq4[(size_t)node * 8 + l];   // self row (pre-scaled by dinv[node])
    acc[0] = bflo(v.x); acc[1] = bfhi(v.x);
    acc[2] = bflo(v.y); acc[3] = bfhi(v.y);
    acc[4] = bflo(v.z); acc[5] = bfhi(v.z);
    acc[6] = bflo(v.w); acc[7] = bfhi(v.w);

    int p = beg;
    for (; p + 2 <= end; p += 2) {
        int s0 = srcIdx[p];
        int s1 = srcIdx[p + 1];
        uint4 v0 = hq4[(size_t)s0 * 8 + l];
        uint4 v1 = hq4[(size_t)s1 * 8 + l];
        acc[0] += bflo(v0.x); acc[1] += bfhi(v0.x);
        acc[2] += bflo(v0.y); acc[3] += bfhi(v0.y);
        acc[4] += bflo(v0.z); acc[5] += bfhi(v0.z);
        acc[6] += bflo(v0.w); acc[7] += bfhi(v0.w);
        acc[0] += bflo(v1.x); acc[1] += bfhi(v1.x);
        acc[2] += bflo(v1.y); acc[3] += bfhi(v1.y);
        acc[4] += bflo(v1.z); acc[5] += bfhi(v1.z);
        acc[6] += bflo(v1.w); acc[7] += bfhi(v1.w);
    }
    if (p < end) {
        int s0 = srcIdx[p];
        uint4 v0 = hq4[(size_t)s0 * 8 + l];
        acc[0] += bflo(v0.x); acc[1] += bfhi(v0.x);
        acc[2] += bflo(v0.y); acc[3] += bfhi(v0.y);
        acc[4] += bflo(v0.z); acc[5] += bfhi(v0.z);
        acc[6] += bflo(v0.w); acc[7] += bfhi(v0.w);
    }

    float di = dinv[node];
    float4 xa = x4[(size_t)node * 16 + l * 2];
    float4 xb = x4[(size_t)node * 16 + l * 2 + 1];
    float4 oa, ob;
    int cb = l * 8;
    oa.x = fmaxf(di * acc[0] + b[cb + 0] + xa.x, 0.f);
    oa.y = fmaxf(di * acc[1] + b[cb + 1] + xa.y, 0.f);
    oa.z = fmaxf(di * acc[2] + b[cb + 2] + xa.z, 0.f);
    oa.w = fmaxf(di * acc[3] + b[cb + 3] + xa.w, 0.f);
    ob.x = fmaxf(di * acc[4] + b[cb + 4] + xb.x, 0.f);
    ob.y = fmaxf(di * acc[5] + b[cb + 5] + xb.y, 0.f);
    ob.z = fmaxf(di * acc[6] + b[cb + 6] + xb.z, 0.f);
    ob.w = fmaxf(di * acc[7] + b[cb + 7] + xb.w, 0.f);
    out4[(size_t)node * 16 + l * 2]     = oa;
    out4[(size_t)node * 16 + l * 2 + 1] = ob;
}

extern "C" void kernel_launch(void* const* d_in, const int* in_sizes, int n_in,
                              void* d_out, int out_size, void* d_ws, size_t ws_size,
                              hipStream_t stream) {
    const float* x = (const float*)d_in[0];
    const float* W = (const float*)d_in[1];
    const float* b = (const float*)d_in[2];
    const int* ei = (const int*)d_in[3];

    char* ws = (char*)d_ws;
    int*    deg    = (int*)(ws + 0);          //   400,000 B
    float*  dinv   = (float*)(ws + 400000);   //   400,000 B
    int*    offs   = (int*)(ws + 800000);     //   400,000 B
    int*    bsum   = (int*)(ws + 1200000);    //       512 B
    int*    srcIdx = (int*)(ws + 1200512);    // 3,200,000 B
    ushort* hq     = (ushort*)(ws + 4400512); // 12,800,000 B

    hipMemsetAsync(deg, 0, NN * sizeof(int), stream);

    deg_kernel<<<(NE + 255) / 256, 256, 0, stream>>>(ei, deg);
    scan1_kernel<<<SCAN_NB, SCAN_B, 0, stream>>>(deg, offs, bsum, dinv);
    scan2_kernel<<<1, 128, 0, stream>>>(bsum);
    bin_kernel<<<(NE + 255) / 256, 256, 0, stream>>>(ei, offs, bsum, srcIdx);
    linear_kernel<<<NN / 16, 256, 0, stream>>>(x, W, dinv, hq);
    gather_kernel<<<NN / 32, 256, 0, stream>>>(srcIdx, deg, offs, bsum, dinv,
                                               (const uint4*)hq, (const float4*)x, b,
                                               (float4*)d_out);
}